// Round 1
// baseline (452.352 us; speedup 1.0000x reference)
//
#include <hip/hip_runtime.h>
#include <hip/hip_bf16.h>
#include <float.h>

#define N_E  1024
#define CD   128
#define QT   64     // queries per block
#define JT   32     // codes per LDS tile

// ---------------- Kernel 1: embed = emb @ proj_w^T + b ; ee[j] = ||embed_j||^2
__global__ __launch_bounds__(128) void k_embed(const float* __restrict__ emb,
                                               const float* __restrict__ pw,
                                               const float* __restrict__ pb,
                                               float* __restrict__ embed,
                                               float* __restrict__ ee) {
    int j = blockIdx.x;
    int c = threadIdx.x;
    __shared__ float er[CD];
    __shared__ float red[CD];
    er[c] = emb[(size_t)j * CD + c];
    __syncthreads();
    float acc = pb[c];
    const float* pwr = pw + (size_t)c * CD;
    #pragma unroll 8
    for (int k = 0; k < CD; ++k) acc += er[k] * pwr[k];
    embed[(size_t)j * CD + c] = acc;
    red[c] = acc * acc;
    __syncthreads();
    for (int off = 64; off > 0; off >>= 1) {
        if (c < off) red[c] += red[c + off];
        __syncthreads();
    }
    if (c == 0) ee[j] = red[0];
}

// ---------------- Kernel 2: fused distances + argmin + online logsumexp + outputs
__global__ __launch_bounds__(256) void k_vq(const float* __restrict__ x,
                                            const float* __restrict__ embed,
                                            const float* __restrict__ ee,
                                            float* __restrict__ out_xq,
                                            float* __restrict__ out_idx,
                                            float* __restrict__ partials) {
    __shared__ float qs[QT * CD];     // swizzled: 16B chunk cc stored at cc^(row&7)
    __shared__ float es[JT * CD];     // linear (broadcast reads)
    __shared__ float ees[JT];
    __shared__ float rD2[4 * QT];
    __shared__ int   rJ [4 * QT];
    __shared__ float rM [4 * QT];
    __shared__ float rS [4 * QT];
    __shared__ int   bestjs[QT];

    const int t  = threadIdx.x;
    const int w  = t >> 6;    // wave id = code sub-slot
    const int l  = t & 63;    // lane = query row
    const int blk = blockIdx.x;
    const int qbase = blk * QT;
    const int b   = qbase >> 10;      // 1024 pixels per image
    const int hw0 = qbase & 1023;

    // ---- stage Q tile: qs[row][c] = x[b, c, hw0+row], swizzled chunks
    const int f4 = t & 15, c0 = t >> 4;
    const float* xb = x + (size_t)b * CD * 1024;
    for (int c = c0; c < CD; c += 16) {
        const float4 v = *reinterpret_cast<const float4*>(xb + (size_t)c * 1024 + hw0 + 4 * f4);
        const float vv[4] = {v.x, v.y, v.z, v.w};
        const int chunk = c >> 2, wi = c & 3;
        #pragma unroll
        for (int k = 0; k < 4; ++k) {
            const int row = 4 * f4 + k;
            qs[row * CD + ((chunk ^ (row & 7)) << 2) + wi] = vv[k];
        }
    }
    __syncthreads();

    // ---- ||q||^2 for this lane's query (each wave computes its own copy)
    float qq = 0.f;
    #pragma unroll 8
    for (int cc = 0; cc < 32; ++cc) {
        const float4 qv = *reinterpret_cast<const float4*>(&qs[l * CD + ((cc ^ (l & 7)) << 2)]);
        qq += qv.x * qv.x + qv.y * qv.y + qv.z * qv.z + qv.w * qv.w;
    }

    float bestD2 = FLT_MAX; int bestJ = 0;
    float m = -FLT_MAX, s = 0.f;
    const int jl0 = w * 8;

    for (int jt = 0; jt < N_E / JT; ++jt) {
        const int jb = jt * JT;
        __syncthreads();   // previous tile fully consumed before overwrite
        #pragma unroll
        for (int r = 0; r < 4; ++r) {
            const int idx4 = t + 256 * r;   // 1024 float4 = 32x128 floats
            *reinterpret_cast<float4*>(&es[idx4 * 4]) =
                *reinterpret_cast<const float4*>(&embed[(size_t)jb * CD + idx4 * 4]);
        }
        if (t < JT) ees[t] = ee[jb + t];
        __syncthreads();

        float acc[8] = {0, 0, 0, 0, 0, 0, 0, 0};
        for (int cc = 0; cc < 32; ++cc) {
            const float4 qv = *reinterpret_cast<const float4*>(&qs[l * CD + ((cc ^ (l & 7)) << 2)]);
            #pragma unroll
            for (int k = 0; k < 8; ++k) {
                const float4 ev = *reinterpret_cast<const float4*>(&es[(jl0 + k) * CD + (cc << 2)]);
                acc[k] = fmaf(qv.x, ev.x, fmaf(qv.y, ev.y, fmaf(qv.z, ev.z, fmaf(qv.w, ev.w, acc[k]))));
            }
        }
        #pragma unroll
        for (int k = 0; k < 8; ++k) {
            const int j = jb + jl0 + k;
            float d2 = qq + ees[jl0 + k] - 2.f * acc[k];
            d2 = fmaxf(d2, 0.f);
            if (d2 < bestD2) { bestD2 = d2; bestJ = j; }   // strict <  => first occurrence
            const float nm = -sqrtf(d2);
            const float newm = fmaxf(m, nm);
            s = s * __expf(m - newm) + __expf(nm - newm);
            m = newm;
        }
    }

    // ---- cross-wave merge (4 partials per query)
    rD2[w * QT + l] = bestD2; rJ[w * QT + l] = bestJ;
    rM [w * QT + l] = m;      rS[w * QT + l] = s;
    __syncthreads();
    if (t < QT) {
        float bD2 = FLT_MAX; int bJ = 0; float M = -FLT_MAX, S = 0.f;
        #pragma unroll
        for (int p = 0; p < 4; ++p) {
            const float d2 = rD2[p * QT + t]; const int jj = rJ[p * QT + t];
            if (d2 < bD2 || (d2 == bD2 && jj < bJ)) { bD2 = d2; bJ = jj; }
            const float pm = rM[p * QT + t], ps = rS[p * QT + t];
            const float nM = fmaxf(M, pm);
            S = S * __expf(M - nM) + ps * __expf(pm - nM);
            M = nM;
        }
        bestjs[t] = bJ;
        out_idx[qbase + t] = (float)bJ;
        float v = __logf(S);            // loss_i = log sum_j exp(d_min - d_j)
        #pragma unroll
        for (int off = 32; off; off >>= 1) v += __shfl_down(v, off);
        if (t == 0) partials[blk] = v;
    }
    __syncthreads();

    // ---- write x_q: out[b, c, hw] = embed[bestj[hw]][c]
    float* ob = out_xq + (size_t)b * CD * 1024 + hw0 + 4 * f4;
    const int j0 = bestjs[4 * f4 + 0], j1 = bestjs[4 * f4 + 1];
    const int j2 = bestjs[4 * f4 + 2], j3 = bestjs[4 * f4 + 3];
    for (int c = c0; c < CD; c += 16) {
        float4 v;
        v.x = embed[(size_t)j0 * CD + c];
        v.y = embed[(size_t)j1 * CD + c];
        v.z = embed[(size_t)j2 * CD + c];
        v.w = embed[(size_t)j3 * CD + c];
        *reinterpret_cast<float4*>(ob + (size_t)c * 1024) = v;
    }
}

// ---------------- Kernel 3: deterministic loss reduction
__global__ __launch_bounds__(256) void k_loss(const float* __restrict__ partials,
                                              float* __restrict__ out_loss) {
    __shared__ float red[256];
    const int t = threadIdx.x;
    float v = 0.f;
    for (int i = t; i < 1024; i += 256) v += partials[i];
    red[t] = v;
    __syncthreads();
    for (int off = 128; off; off >>= 1) {
        if (t < off) red[t] += red[t + off];
        __syncthreads();
    }
    if (t == 0) out_loss[0] = red[0] * (1.0f / 65536.0f);
}

extern "C" void kernel_launch(void* const* d_in, const int* in_sizes, int n_in,
                              void* d_out, int out_size, void* d_ws, size_t ws_size,
                              hipStream_t stream) {
    const float* x   = (const float*)d_in[0];   // (64,128,32,32)
    const float* emb = (const float*)d_in[1];   // (1024,128)
    const float* pw  = (const float*)d_in[2];   // (128,128)
    const float* pb  = (const float*)d_in[3];   // (128,)

    float* out = (float*)d_out;
    float* out_xq   = out;                 // 8388608 floats
    float* out_loss = out + 8388608;       // 1 float
    float* out_idx  = out + 8388609;       // 65536 floats

    float* embed    = (float*)d_ws;        // 1024*128
    float* ee       = embed + N_E * CD;    // 1024
    float* partials = ee + N_E;            // 1024

    k_embed<<<N_E, 128, 0, stream>>>(emb, pw, pb, embed, ee);
    k_vq<<<65536 / QT, 256, 0, stream>>>(x, embed, ee, out_xq, out_idx, partials);
    k_loss<<<1, 256, 0, stream>>>(partials, out_loss);
}

// Round 3
// 331.395 us; speedup vs baseline: 1.3650x; 1.3650x over previous
//
#include <hip/hip_runtime.h>
#include <hip/hip_bf16.h>
#include <float.h>

#define N_E   1024
#define CD    128
#define DELTA 0.0625f

typedef __attribute__((ext_vector_type(4))) float f32x4;
typedef __attribute__((ext_vector_type(8))) short bf16x8;

static __device__ inline unsigned short f2bf(float f) {
    unsigned u = __float_as_uint(f);
    unsigned r = (u + 0x7fffu + ((u >> 16) & 1u)) >> 16;
    return (unsigned short)r;
}
static __device__ inline float bf2f(unsigned short s) {
    return __uint_as_float(((unsigned)s) << 16);
}

// ---------------- Kernel 1: embed = emb @ proj_w^T + b ; ee ; Ecat = [ehi|ehi|elo] bf16
__global__ __launch_bounds__(128) void k_embed(const float* __restrict__ emb,
                                               const float* __restrict__ pw,
                                               const float* __restrict__ pb,
                                               float* __restrict__ embed,
                                               float* __restrict__ ee,
                                               unsigned short* __restrict__ ecat) {
    int j = blockIdx.x;
    int c = threadIdx.x;
    __shared__ float er[CD];
    __shared__ float red[CD];
    er[c] = emb[(size_t)j * CD + c];
    __syncthreads();
    float acc = pb[c];
    const float* pwr = pw + (size_t)c * CD;
    #pragma unroll 8
    for (int k = 0; k < CD; ++k) acc += er[k] * pwr[k];
    embed[(size_t)j * CD + c] = acc;
    const unsigned short h = f2bf(acc);
    const unsigned short l = f2bf(acc - bf2f(h));
    ecat[(size_t)j * 384 + c]       = h;
    ecat[(size_t)j * 384 + 128 + c] = h;
    ecat[(size_t)j * 384 + 256 + c] = l;
    red[c] = acc * acc;
    __syncthreads();
    for (int off = 64; off > 0; off >>= 1) {
        if (c < off) red[c] += red[c + off];
        __syncthreads();
    }
    if (c == 0) ee[j] = red[0];
}

// ---------------- Kernel 2: MFMA split-bf16 distances + argmin(+margin recheck) + LSE
__global__ __launch_bounds__(256) void k_vq(const float* __restrict__ x,
                                            const float* __restrict__ embed,
                                            const float* __restrict__ ee,
                                            const unsigned short* __restrict__ ecat,
                                            float* __restrict__ out_xq,
                                            float* __restrict__ out_idx,
                                            float* __restrict__ partials) {
    // lds_q: [m][32 chunks of 8 shorts]; chunk cc of row m stored at cc ^ SW(m),
    // SW(m) = (m&15) ^ (m>>4)  -- SAME function on write and read sides.
    __shared__ alignas(16) unsigned short lds_q[64 * 256];
    __shared__ float qq[64];
    __shared__ float qqpart[4][64];
    __shared__ alignas(16) float wstate[4 * 64 * 4];   // per (wave,m): b1, j1(bits), b2, s
    __shared__ int   bestjs[64];
    __shared__ unsigned long long flagmask_s;
    __shared__ alignas(16) float qbuf[4 * 128];

    const int t    = threadIdx.x;
    const int w    = t >> 6;
    const int lane = t & 63;
    const int lo4  = lane & 15;
    const int hi2  = lane >> 4;
    const int blk  = blockIdx.x;
    const int qbase = blk * 64;
    const int b    = qbase >> 10;
    const int hw0  = qbase & 1023;
    const float* xb = x + (size_t)b * 131072;

    // ---- stage Q: hi/lo bf16 into swizzled LDS + per-m ||q||^2 partials
    const int m4 = t & 15;
    float qql[4] = {0.f, 0.f, 0.f, 0.f};
    #pragma unroll
    for (int r = 0; r < 8; ++r) {
        const int c = (t >> 4) + 16 * r;
        const float4 v = *reinterpret_cast<const float4*>(xb + c * 1024 + hw0 + 4 * m4);
        const float vv[4] = {v.x, v.y, v.z, v.w};
        #pragma unroll
        for (int i = 0; i < 4; ++i) {
            const int m = 4 * m4 + i;
            const int sw = (m & 15) ^ (m >> 4);
            const float f = vv[i];
            qql[i] = fmaf(f, f, qql[i]);
            const unsigned short h = f2bf(f);
            const unsigned short l = f2bf(f - bf2f(h));
            const int ch_h = (c >> 3) ^ sw;
            const int ch_l = (16 + (c >> 3)) ^ sw;
            lds_q[m * 256 + ch_h * 8 + (c & 7)] = h;
            lds_q[m * 256 + ch_l * 8 + (c & 7)] = l;
        }
    }
    #pragma unroll
    for (int i = 0; i < 4; ++i) {
        qql[i] += __shfl_xor(qql[i], 16);
        qql[i] += __shfl_xor(qql[i], 32);
    }
    if (lane < 16) {
        #pragma unroll
        for (int i = 0; i < 4; ++i) qqpart[w][4 * lane + i] = qql[i];
    }
    __syncthreads();
    if (t < 64) qq[t] = qqpart[0][t] + qqpart[1][t] + qqpart[2][t] + qqpart[3][t];
    __syncthreads();

    // ---- per-lane persistent state (slot = tm*4 + r; m = tm*16 + hi2*4 + r)
    float qq_s[16];
    #pragma unroll
    for (int tm = 0; tm < 4; ++tm)
        #pragma unroll
        for (int r = 0; r < 4; ++r) qq_s[tm * 4 + r] = qq[tm * 16 + hi2 * 4 + r];

    float b1[16], b2[16], sacc[16];
    int   j1[16];
    #pragma unroll
    for (int s = 0; s < 16; ++s) { b1[s] = FLT_MAX; b2[s] = FLT_MAX; sacc[s] = 0.f; j1[s] = 0; }

    const int nw0 = w * 256;
    #pragma unroll 1
    for (int nc = 0; nc < 4; ++nc) {
        const int nb = nw0 + nc * 64;
        float ee_r[4];
        #pragma unroll
        for (int tn = 0; tn < 4; ++tn) ee_r[tn] = ee[nb + tn * 16 + lo4];

        f32x4 acc[4][4];
        const f32x4 zero = {0.f, 0.f, 0.f, 0.f};
        #pragma unroll
        for (int tm = 0; tm < 4; ++tm)
            #pragma unroll
            for (int tn = 0; tn < 4; ++tn) acc[tm][tn] = zero;

        #pragma unroll
        for (int ks = 0; ks < 12; ++ks) {
            // A phys k: seg0(qhi) for ks 0..3, seg1(qlo) for ks 4..7, seg0(qhi) for ks 8..11
            const int akb = ((ks >= 8) ? (ks - 8) : ks) * 32 + hi2 * 8;
            bf16x8 a[4];
            #pragma unroll
            for (int tm = 0; tm < 4; ++tm) {
                const int sw = lo4 ^ tm;          // SW(m) for m = tm*16 + lo4
                const int ch = (akb >> 3) ^ sw;
                a[tm] = *reinterpret_cast<const bf16x8*>(&lds_q[(tm * 16 + lo4) * 256 + ch * 8]);
            }
            const int bk = ks * 32 + hi2 * 8;     // Ecat k (0..383)
            bf16x8 bf[4];
            #pragma unroll
            for (int tn = 0; tn < 4; ++tn) {
                const int n = nb + tn * 16 + lo4;
                bf[tn] = *reinterpret_cast<const bf16x8*>(&ecat[n * 384 + bk]);
            }
            #pragma unroll
            for (int tn = 0; tn < 4; ++tn)
                #pragma unroll
                for (int tm = 0; tm < 4; ++tm)
                    acc[tm][tn] = __builtin_amdgcn_mfma_f32_16x16x32_bf16(a[tm], bf[tn], acc[tm][tn], 0, 0, 0);
        }

        // ---- fold: d2 = qq + ee - 2*dot ; top-2 ; fixed-frame LSE
        #pragma unroll
        for (int tm = 0; tm < 4; ++tm)
            #pragma unroll
            for (int tn = 0; tn < 4; ++tn) {
                const int n = nb + tn * 16 + lo4;
                #pragma unroll
                for (int r = 0; r < 4; ++r) {
                    const int slot = tm * 4 + r;
                    float d2 = fmaf(-2.f, acc[tm][tn][r], qq_s[slot] + ee_r[tn]);
                    d2 = fmaxf(d2, 0.f);
                    b2[slot] = fminf(b2[slot], fmaxf(b1[slot], d2));
                    const bool lt = d2 < b1[slot];
                    j1[slot] = lt ? n : j1[slot];
                    b1[slot] = lt ? d2 : b1[slot];
                    sacc[slot] += __expf(16.f - sqrtf(d2));
                }
            }
    }

    // ---- 16-lane-group merge per slot, write per-wave state
    #pragma unroll
    for (int slot = 0; slot < 16; ++slot) {
        float B1 = b1[slot]; int J1 = j1[slot]; float B2 = b2[slot]; float S = sacc[slot];
        #pragma unroll
        for (int d = 1; d <= 8; d <<= 1) {
            const float o1 = __shfl_xor(B1, d);
            const int   oj = __shfl_xor(J1, d);
            const float o2 = __shfl_xor(B2, d);
            const float os = __shfl_xor(S, d);
            const float mx = fmaxf(B1, o1);
            B2 = fminf(fminf(B2, o2), mx);
            const bool take = (o1 < B1) || (o1 == B1 && oj < J1);
            B1 = take ? o1 : B1;
            J1 = take ? oj : J1;
            S += os;
        }
        if (lo4 == 0) {
            const int m = (slot >> 2) * 16 + hi2 * 4 + (slot & 3);
            f32x4 st = {B1, __int_as_float(J1), B2, S};
            *reinterpret_cast<f32x4*>(&wstate[(w * 64 + m) * 4]) = st;
        }
    }
    __syncthreads();

    // ---- cross-wave merge, flags, loss partial
    if (t < 64) {
        float B1 = FLT_MAX; int J1 = 0; float B2 = FLT_MAX; float S = 0.f;
        #pragma unroll
        for (int ww = 0; ww < 4; ++ww) {
            const f32x4 st = *reinterpret_cast<const f32x4*>(&wstate[(ww * 64 + t) * 4]);
            const float c1 = st[0]; const int i1 = __float_as_int(st[1]);
            const float c2 = st[2]; const float cs = st[3];
            const float mx = fmaxf(B1, c1);
            B2 = fminf(fminf(B2, c2), mx);
            const bool take = (c1 < B1) || (c1 == B1 && i1 < J1);
            B1 = take ? c1 : B1;
            J1 = take ? i1 : J1;
            S += cs;
        }
        bestjs[t] = J1;
        out_idx[qbase + t] = (float)J1;
        const bool fl = (B2 - B1) < DELTA;
        const unsigned long long bal = __ballot(fl);
        if (t == 0) flagmask_s = bal;
        float lossi = sqrtf(fmaxf(B1, 0.f)) - 16.f + __logf(S);
        #pragma unroll
        for (int d = 32; d; d >>= 1) lossi += __shfl_down(lossi, d);
        if (t == 0) partials[blk] = lossi;
    }
    __syncthreads();

    // ---- exact fp32 recheck for flagged (near-tie) queries
    unsigned long long fm = flagmask_s;
    int kq = 0;
    while (fm) {
        const int m = __builtin_ctzll(fm);
        fm &= fm - 1;
        if ((kq & 3) == w) {
            qbuf[w * 128 + lane]      = xb[lane * 1024 + hw0 + m];
            qbuf[w * 128 + 64 + lane] = xb[(lane + 64) * 1024 + hw0 + m];
            __threadfence_block();
            const float qqm = qq[m];
            float dbest = FLT_MAX; int jbest = 0;
            for (int tt = 0; tt < 16; ++tt) {
                const int j = tt * 64 + lane;
                float dot = 0.f;
                #pragma unroll 8
                for (int c4 = 0; c4 < 32; ++c4) {
                    const f32x4 evv = *reinterpret_cast<const f32x4*>(&embed[j * 128 + 4 * c4]);
                    const f32x4 qv  = *reinterpret_cast<const f32x4*>(&qbuf[w * 128 + 4 * c4]);
                    dot = fmaf(evv[0], qv[0], dot);
                    dot = fmaf(evv[1], qv[1], dot);
                    dot = fmaf(evv[2], qv[2], dot);
                    dot = fmaf(evv[3], qv[3], dot);
                }
                float d2 = fmaf(-2.f, dot, qqm + ee[j]);
                d2 = fmaxf(d2, 0.f);
                if (d2 < dbest || (d2 == dbest && j < jbest)) { dbest = d2; jbest = j; }
            }
            #pragma unroll
            for (int d = 1; d <= 32; d <<= 1) {
                const float od = __shfl_xor(dbest, d);
                const int   oj = __shfl_xor(jbest, d);
                if (od < dbest || (od == dbest && oj < jbest)) { dbest = od; jbest = oj; }
            }
            if (lane == 0) {
                bestjs[m] = jbest;
                out_idx[qbase + m] = (float)jbest;
            }
        }
        ++kq;
    }
    __syncthreads();

    // ---- gather x_q
    const int jq0 = bestjs[4 * m4 + 0];
    const int jq1 = bestjs[4 * m4 + 1];
    const int jq2 = bestjs[4 * m4 + 2];
    const int jq3 = bestjs[4 * m4 + 3];
    float* ob = out_xq + (size_t)b * 131072 + hw0 + 4 * m4;
    #pragma unroll
    for (int r = 0; r < 8; ++r) {
        const int c = (t >> 4) + 16 * r;
        float4 v;
        v.x = embed[jq0 * 128 + c];
        v.y = embed[jq1 * 128 + c];
        v.z = embed[jq2 * 128 + c];
        v.w = embed[jq3 * 128 + c];
        *reinterpret_cast<float4*>(ob + (size_t)c * 1024) = v;
    }
}

// ---------------- Kernel 3: deterministic loss reduction
__global__ __launch_bounds__(256) void k_loss(const float* __restrict__ partials,
                                              float* __restrict__ out_loss) {
    __shared__ float red[256];
    const int t = threadIdx.x;
    float v = 0.f;
    for (int i = t; i < 1024; i += 256) v += partials[i];
    red[t] = v;
    __syncthreads();
    for (int off = 128; off; off >>= 1) {
        if (t < off) red[t] += red[t + off];
        __syncthreads();
    }
    if (t == 0) out_loss[0] = red[0] * (1.0f / 65536.0f);
}

extern "C" void kernel_launch(void* const* d_in, const int* in_sizes, int n_in,
                              void* d_out, int out_size, void* d_ws, size_t ws_size,
                              hipStream_t stream) {
    const float* x   = (const float*)d_in[0];   // (64,128,32,32)
    const float* emb = (const float*)d_in[1];   // (1024,128)
    const float* pw  = (const float*)d_in[2];   // (128,128)
    const float* pb  = (const float*)d_in[3];   // (128,)

    float* out = (float*)d_out;
    float* out_xq   = out;                 // 8388608 floats
    float* out_loss = out + 8388608;       // 1 float
    float* out_idx  = out + 8388609;       // 65536 floats

    float* embed    = (float*)d_ws;                    // 1024*128 fp32
    float* ee       = embed + N_E * CD;                // 1024
    float* partials = ee + N_E;                        // 1024
    unsigned short* ecat = (unsigned short*)(partials + 1024);  // 1024*384 bf16

    k_embed<<<N_E, 128, 0, stream>>>(emb, pw, pb, embed, ee, ecat);
    k_vq<<<65536 / 64, 256, 0, stream>>>(x, embed, ee, ecat, out_xq, out_idx, partials);
    k_loss<<<1, 256, 0, stream>>>(partials, out_loss);
}

// Round 5
// 275.665 us; speedup vs baseline: 1.6409x; 1.2022x over previous
//
#include <hip/hip_runtime.h>
#include <hip/hip_bf16.h>
#include <float.h>

#define N_E   1024
#define CD    128
#define DELTA 0.0625f

typedef __attribute__((ext_vector_type(4))) float f32x4;
typedef __attribute__((ext_vector_type(8))) short bf16x8;

static __device__ inline unsigned short f2bf(float f) {
    unsigned u = __float_as_uint(f);
    unsigned r = (u + 0x7fffu + ((u >> 16) & 1u)) >> 16;
    return (unsigned short)r;
}
static __device__ inline float bf2f(unsigned short s) {
    return __uint_as_float(((unsigned)s) << 16);
}

// ---------------- Kernel 1: embed = emb @ proj_w^T + b ; ee ; ehi/elo split bf16
__global__ __launch_bounds__(128) void k_embed(const float* __restrict__ emb,
                                               const float* __restrict__ pw,
                                               const float* __restrict__ pb,
                                               float* __restrict__ embed,
                                               float* __restrict__ ee,
                                               unsigned short* __restrict__ ehi,
                                               unsigned short* __restrict__ elo) {
    int j = blockIdx.x;
    int c = threadIdx.x;
    __shared__ float er[CD];
    __shared__ float red[CD];
    er[c] = emb[(size_t)j * CD + c];
    __syncthreads();
    float acc = pb[c];
    const float* pwr = pw + (size_t)c * CD;
    #pragma unroll 8
    for (int k = 0; k < CD; ++k) acc += er[k] * pwr[k];
    embed[(size_t)j * CD + c] = acc;
    const unsigned short h = f2bf(acc);
    const unsigned short l = f2bf(acc - bf2f(h));
    ehi[(size_t)j * CD + c] = h;
    elo[(size_t)j * CD + c] = l;
    red[c] = acc * acc;
    __syncthreads();
    for (int off = 64; off > 0; off >>= 1) {
        if (c < off) red[c] += red[c + off];
        __syncthreads();
    }
    if (c == 0) ee[j] = red[0];
}

// ---------------- Kernel 2: MFMA split-bf16, A-in-regs, LDS-dbuf B, M-split waves
__global__ __launch_bounds__(256) void k_vq(const float* __restrict__ x,
                                            const float* __restrict__ ee,
                                            const unsigned short* __restrict__ ehi,
                                            const unsigned short* __restrict__ elo,
                                            const float* __restrict__ embed,
                                            float* __restrict__ out_xq,
                                            float* __restrict__ out_idx,
                                            float* __restrict__ partials) {
    // smem (64 KB) phase 1: x-tile [128 rows][32 chunks of 8 shorts], chunk cc at cc^SW(m),
    //                       SW(m) = (m&15) ^ (m>>4)
    // smem phase 2: B dbuf: buf(16384 shorts) = ehi-tile [64][128] + elo-tile [64][128],
    //               chunk s of row n holds global chunk s ^ (n&7)  (linear dest, swizzled src)
    __shared__ alignas(64) unsigned short smem[2 * 16384];
    __shared__ float qq[128];
    __shared__ float qqpart[4][128];
    __shared__ float ee_s[N_E];
    __shared__ int   bestjs[128];
    __shared__ unsigned flagm[4];
    __shared__ alignas(16) float qbuf[4][128];

    const int t    = threadIdx.x;
    const int w    = t >> 6;
    const int lane = t & 63;
    const int lo4  = lane & 15;
    const int hi2  = lane >> 4;
    const int blk  = blockIdx.x;
    const int qbase = blk * 128;
    const int b    = blk >> 3;
    const int hw0  = (blk & 7) * 128;
    const float* xb = x + (size_t)b * 131072;

    if (t < 4) flagm[t] = 0;
    for (int i = t; i < N_E; i += 256) ee_s[i] = ee[i];

    // ---- phase A: stage x-tile as hi/lo bf16 (swizzled) + qq partials
    const int f4 = t & 31;      // query group: queries 4*f4 .. 4*f4+3
    const int cg = t >> 5;      // channel group: channels cg*16 .. cg*16+15
    float qql[4] = {0.f, 0.f, 0.f, 0.f};
    #pragma unroll
    for (int r = 0; r < 16; ++r) {
        const int c = cg * 16 + r;
        const float4 v = *reinterpret_cast<const float4*>(xb + (size_t)c * 1024 + hw0 + 4 * f4);
        const float vv[4] = {v.x, v.y, v.z, v.w};
        #pragma unroll
        for (int i = 0; i < 4; ++i) {
            const int m = 4 * f4 + i;
            const int sw = (m & 15) ^ (m >> 4);
            const float f = vv[i];
            qql[i] = fmaf(f, f, qql[i]);
            const unsigned short h = f2bf(f);
            const unsigned short l = f2bf(f - bf2f(h));
            const int ch = c >> 3;
            smem[m * 256 + ((ch ^ sw) << 3) + (c & 7)]        = h;
            smem[m * 256 + (((16 + ch) ^ sw) << 3) + (c & 7)] = l;
        }
    }
    #pragma unroll
    for (int i = 0; i < 4; ++i) qql[i] += __shfl_xor(qql[i], 32);
    if (lane < 32) {
        #pragma unroll
        for (int i = 0; i < 4; ++i) qqpart[w][4 * lane + i] = qql[i];
    }
    __syncthreads();
    if (t < 128) qq[t] = qqpart[0][t] + qqpart[1][t] + qqpart[2][t] + qqpart[3][t];
    __syncthreads();

    // ---- A-fragments (qhi, qlo) into registers; wave owns rows mb..mb+31
    const int mb = w * 32;
    bf16x8 a_hi[2][4], a_lo[2][4];
    #pragma unroll
    for (int tm = 0; tm < 2; ++tm) {
        const int m = mb + tm * 16 + lo4;
        const int sw = (m & 15) ^ (m >> 4);
        #pragma unroll
        for (int ks = 0; ks < 4; ++ks) {
            const int kc = ks * 4 + hi2;
            a_hi[tm][ks] = *reinterpret_cast<const bf16x8*>(&smem[m * 256 + ((kc ^ sw) << 3)]);
            a_lo[tm][ks] = *reinterpret_cast<const bf16x8*>(&smem[m * 256 + (((16 + kc) ^ sw) << 3)]);
        }
    }
    float qq_s[8];
    #pragma unroll
    for (int tm = 0; tm < 2; ++tm)
        #pragma unroll
        for (int r = 0; r < 4; ++r) qq_s[tm * 4 + r] = qq[mb + tm * 16 + hi2 * 4 + r];

    asm volatile("s_waitcnt lgkmcnt(0)" ::: "memory");
    __builtin_amdgcn_sched_barrier(0);
    __syncthreads();   // all waves done reading x-region; safe to overwrite with B tiles

    // ---- B tile staging: global_load_lds, linear LDS dest, swizzled global src
    auto stage = [&](int jb, int bufsel) {
        #pragma unroll
        for (int j = 0; j < 8; ++j) {
            const int cidx = w * 512 + j * 64 + lane;      // chunk index in buffer
            const int seg  = cidx >> 10;                   // 0: ehi, 1: elo
            const int rr   = cidx & 1023;
            const int n    = rr >> 4;
            const int s    = rr & 15;
            const int g    = s ^ (n & 7);
            const unsigned short* src = (seg ? elo : ehi) + (size_t)(jb + n) * CD + g * 8;
            unsigned short* dst = &smem[bufsel * 16384 + w * 4096 + j * 512];  // wave-uniform
            __builtin_amdgcn_global_load_lds(
                (const __attribute__((address_space(1))) void*)src,
                (__attribute__((address_space(3))) void*)dst, 16, 0, 0);
        }
    };

    stage(0, 0);
    stage(64, 1);

    float b1[8], b2[8], sacc[8];
    int   j1[8];
    #pragma unroll
    for (int s = 0; s < 8; ++s) { b1[s] = FLT_MAX; b2[s] = FLT_MAX; sacc[s] = 0.f; j1[s] = 0; }

    #pragma unroll 1
    for (int tile = 0; tile < 16; ++tile) {
        if (tile < 15) { asm volatile("s_waitcnt vmcnt(8)" ::: "memory"); }
        else           { asm volatile("s_waitcnt vmcnt(0)" ::: "memory"); }
        __builtin_amdgcn_sched_barrier(0);
        __builtin_amdgcn_s_barrier();
        __builtin_amdgcn_sched_barrier(0);

        const unsigned short* bb = &smem[(tile & 1) * 16384];
        const int jb = tile * 64;
        float ee_r[4];
        #pragma unroll
        for (int tn = 0; tn < 4; ++tn) ee_r[tn] = ee_s[jb + tn * 16 + lo4];

        f32x4 acc[2][4];
        const f32x4 zero = {0.f, 0.f, 0.f, 0.f};
        #pragma unroll
        for (int tm = 0; tm < 2; ++tm)
            #pragma unroll
            for (int tn = 0; tn < 4; ++tn) acc[tm][tn] = zero;

        // pass 0: qhi·ehi ; pass 1: qlo·ehi ; pass 2: qhi·elo
        #pragma unroll
        for (int p = 0; p < 3; ++p) {
            const int segoff = (p == 2) ? 8192 : 0;
            #pragma unroll
            for (int ks = 0; ks < 4; ++ks) {
                const int kc = ks * 4 + hi2;
                bf16x8 bfr[4];
                #pragma unroll
                for (int tn = 0; tn < 4; ++tn) {
                    const int n = tn * 16 + lo4;
                    bfr[tn] = *reinterpret_cast<const bf16x8*>(
                        &bb[segoff + n * CD + ((kc ^ (n & 7)) << 3)]);
                }
                #pragma unroll
                for (int tn = 0; tn < 4; ++tn)
                    #pragma unroll
                    for (int tm = 0; tm < 2; ++tm)
                        acc[tm][tn] = __builtin_amdgcn_mfma_f32_16x16x32_bf16(
                            (p == 1) ? a_lo[tm][ks] : a_hi[tm][ks], bfr[tn], acc[tm][tn], 0, 0, 0);
            }
        }

        // ---- fold: d2 ; top-2 ; fixed-frame LSE
        #pragma unroll
        for (int tm = 0; tm < 2; ++tm)
            #pragma unroll
            for (int tn = 0; tn < 4; ++tn) {
                const int n = jb + tn * 16 + lo4;
                #pragma unroll
                for (int r = 0; r < 4; ++r) {
                    const int slot = tm * 4 + r;
                    float d2 = fmaf(-2.f, acc[tm][tn][r], qq_s[slot] + ee_r[tn]);
                    d2 = fmaxf(d2, 0.f);
                    b2[slot] = fminf(b2[slot], fmaxf(b1[slot], d2));
                    const bool lt = d2 < b1[slot];
                    j1[slot] = lt ? n : j1[slot];
                    b1[slot] = lt ? d2 : b1[slot];
                    const float sd = sqrtf(d2);
                    sacc[slot] += __expf(16.f - sd);
                }
            }

        asm volatile("s_waitcnt lgkmcnt(0)" ::: "memory");
        __builtin_amdgcn_sched_barrier(0);
        __builtin_amdgcn_s_barrier();   // all waves done reading buf before overwrite
        __builtin_amdgcn_sched_barrier(0);
        if (tile < 14) stage(jb + 128, tile & 1);
    }

    // ---- per-wave final merge across lo4, flags, loss
    unsigned flagbits = 0;
    float lsum = 0.f;
    #pragma unroll
    for (int slot = 0; slot < 8; ++slot) {
        float B1 = b1[slot]; int J1 = j1[slot]; float B2 = b2[slot]; float S = sacc[slot];
        #pragma unroll
        for (int d = 1; d <= 8; d <<= 1) {
            const float o1 = __shfl_xor(B1, d);
            const int   oj = __shfl_xor(J1, d);
            const float o2 = __shfl_xor(B2, d);
            const float os = __shfl_xor(S, d);
            const float mx = fmaxf(B1, o1);
            B2 = fminf(fminf(B2, o2), mx);
            const bool take = (o1 < B1) || (o1 == B1 && oj < J1);
            B1 = take ? o1 : B1;
            J1 = take ? oj : J1;
            S += os;
        }
        if (lo4 == 0) {
            const int mloc = (slot >> 2) * 16 + hi2 * 4 + (slot & 3);
            bestjs[mb + mloc] = J1;
            out_idx[qbase + mb + mloc] = (float)J1;
            if (B2 - B1 < DELTA) flagbits |= (1u << mloc);
            lsum += sqrtf(fmaxf(B1, 0.f)) - 16.f + __logf(S);
        }
    }
    if (lo4 == 0) atomicOr(&flagm[w], flagbits);
    lsum += __shfl_down(lsum, 16);
    lsum += __shfl_down(lsum, 32);
    if (lane == 0) partials[blk * 4 + w] = lsum;
    __syncthreads();

    // ---- exact fp32 recheck for near-tie queries (per wave, own rows)
    unsigned fm = flagm[w];
    while (fm) {
        const int mloc = __builtin_ctz(fm);
        fm &= fm - 1;
        const int m = mb + mloc;
        const int hw = hw0 + m;
        qbuf[w][lane]      = xb[(size_t)lane * 1024 + hw];
        qbuf[w][64 + lane] = xb[(size_t)(lane + 64) * 1024 + hw];
        __threadfence_block();
        const float qqm = qq[m];
        float dbest = FLT_MAX; int jbest = 0;
        for (int tt = 0; tt < 16; ++tt) {
            const int j = tt * 64 + lane;
            float dot = 0.f;
            #pragma unroll 8
            for (int c4 = 0; c4 < 32; ++c4) {
                const f32x4 evv = *reinterpret_cast<const f32x4*>(&embed[j * CD + 4 * c4]);
                const f32x4 qv  = *reinterpret_cast<const f32x4*>(&qbuf[w][4 * c4]);
                dot = fmaf(evv[0], qv[0], dot);
                dot = fmaf(evv[1], qv[1], dot);
                dot = fmaf(evv[2], qv[2], dot);
                dot = fmaf(evv[3], qv[3], dot);
            }
            float d2 = fmaf(-2.f, dot, qqm + ee_s[j]);
            d2 = fmaxf(d2, 0.f);
            if (d2 < dbest || (d2 == dbest && j < jbest)) { dbest = d2; jbest = j; }
        }
        #pragma unroll
        for (int d = 1; d <= 32; d <<= 1) {
            const float od = __shfl_xor(dbest, d);
            const int   oj = __shfl_xor(jbest, d);
            if (od < dbest || (od == dbest && oj < jbest)) { dbest = od; jbest = oj; }
        }
        if (lane == 0) {
            bestjs[m] = jbest;
            out_idx[qbase + m] = (float)jbest;
        }
    }
    __syncthreads();

    // ---- gather x_q
    const int jq0 = bestjs[4 * f4 + 0];
    const int jq1 = bestjs[4 * f4 + 1];
    const int jq2 = bestjs[4 * f4 + 2];
    const int jq3 = bestjs[4 * f4 + 3];
    float* ob = out_xq + (size_t)b * 131072 + hw0 + 4 * f4;
    #pragma unroll
    for (int r = 0; r < 16; ++r) {
        const int c = cg * 16 + r;
        float4 v;
        v.x = embed[jq0 * CD + c];
        v.y = embed[jq1 * CD + c];
        v.z = embed[jq2 * CD + c];
        v.w = embed[jq3 * CD + c];
        *reinterpret_cast<float4*>(ob + (size_t)c * 1024) = v;
    }
}

// ---------------- Kernel 3: deterministic loss reduction
__global__ __launch_bounds__(256) void k_loss(const float* __restrict__ partials,
                                              float* __restrict__ out_loss) {
    __shared__ float red[256];
    const int t = threadIdx.x;
    float v = 0.f;
    for (int i = t; i < 2048; i += 256) v += partials[i];
    red[t] = v;
    __syncthreads();
    for (int off = 128; off; off >>= 1) {
        if (t < off) red[t] += red[t + off];
        __syncthreads();
    }
    if (t == 0) out_loss[0] = red[0] * (1.0f / 65536.0f);
}

extern "C" void kernel_launch(void* const* d_in, const int* in_sizes, int n_in,
                              void* d_out, int out_size, void* d_ws, size_t ws_size,
                              hipStream_t stream) {
    const float* x   = (const float*)d_in[0];   // (64,128,32,32)
    const float* emb = (const float*)d_in[1];   // (1024,128)
    const float* pw  = (const float*)d_in[2];   // (128,128)
    const float* pb  = (const float*)d_in[3];   // (128,)

    float* out = (float*)d_out;
    float* out_xq   = out;                 // 8388608 floats
    float* out_loss = out + 8388608;       // 1 float
    float* out_idx  = out + 8388609;       // 65536 floats

    float* embed    = (float*)d_ws;                       // 1024*128 fp32
    float* ee       = embed + N_E * CD;                   // 1024
    float* partials = ee + N_E;                           // 2048
    unsigned short* ehi = (unsigned short*)(partials + 2048);   // 1024*128 bf16
    unsigned short* elo = ehi + N_E * CD;                       // 1024*128 bf16

    k_embed<<<N_E, 128, 0, stream>>>(emb, pw, pb, embed, ee, ehi, elo);
    k_vq<<<512, 256, 0, stream>>>(x, ee, ehi, elo, embed, out_xq, out_idx, partials);
    k_loss<<<1, 256, 0, stream>>>(partials, out_loss);
}

// Round 6
// 225.759 us; speedup vs baseline: 2.0037x; 1.2211x over previous
//
#include <hip/hip_runtime.h>
#include <hip/hip_bf16.h>
#include <float.h>

#define N_E   1024
#define CD    128
#define DELTA 0.0625f

typedef __attribute__((ext_vector_type(4))) float f32x4;
typedef __attribute__((ext_vector_type(8))) short bf16x8;

static __device__ inline unsigned short f2bf(float f) {
    unsigned u = __float_as_uint(f);
    unsigned r = (u + 0x7fffu + ((u >> 16) & 1u)) >> 16;
    return (unsigned short)r;
}
static __device__ inline float bf2f(unsigned short s) {
    return __uint_as_float(((unsigned)s) << 16);
}

// ---------------- Kernel 1: embed = emb @ proj_w^T + b ; ee ; ehi/elo split bf16
__global__ __launch_bounds__(128) void k_embed(const float* __restrict__ emb,
                                               const float* __restrict__ pw,
                                               const float* __restrict__ pb,
                                               float* __restrict__ embed,
                                               float* __restrict__ ee,
                                               unsigned short* __restrict__ ehi,
                                               unsigned short* __restrict__ elo) {
    int j = blockIdx.x;
    int c = threadIdx.x;
    __shared__ float er[CD];
    __shared__ float red[CD];
    er[c] = emb[(size_t)j * CD + c];
    __syncthreads();
    float acc = pb[c];
    const float* pwr = pw + (size_t)c * CD;
    #pragma unroll 8
    for (int k = 0; k < CD; ++k) acc += er[k] * pwr[k];
    embed[(size_t)j * CD + c] = acc;
    const unsigned short h = f2bf(acc);
    const unsigned short l = f2bf(acc - bf2f(h));
    ehi[(size_t)j * CD + c] = h;
    elo[(size_t)j * CD + c] = l;
    red[c] = acc * acc;
    __syncthreads();
    for (int off = 64; off > 0; off >>= 1) {
        if (c < off) red[c] += red[c + off];
        __syncthreads();
    }
    if (c == 0) ee[j] = red[0];
}

// ---------------- Kernel 2: 8-wave M-split, MFMA split-bf16, 2-phase B dbuf
__global__ __launch_bounds__(512, 4) void k_vq(const float* __restrict__ x,
                                               const float* __restrict__ ee,
                                               const unsigned short* __restrict__ ehi,
                                               const unsigned short* __restrict__ elo,
                                               const float* __restrict__ embed,
                                               float* __restrict__ out_xq,
                                               float* __restrict__ out_idx,
                                               float* __restrict__ partials) {
    // Phase 1: smem = x-tile [128 rows][32 chunks of 8 shorts], chunk cc stored at cc^SW(m),
    //          SW(m) = (m&15)^(m>>4); chunks 0-15 = qhi, 16-31 = qlo.
    // Phase 2: smem = B dbuf, each buf 16384 shorts = ehi[64][128] + elo[64][128];
    //          LDS slot s of row n holds global chunk s^(n&15) (linear dest, swizzled src).
    __shared__ alignas(64) unsigned short smem[2 * 16384];
    __shared__ float qq[128];
    __shared__ float qqpart[8][128];
    __shared__ float ee_s[N_E];
    __shared__ int   bestjs[128];
    __shared__ unsigned flagm[8];
    __shared__ alignas(16) float qbuf[8][128];

    const int t    = threadIdx.x;
    const int w    = t >> 6;          // 8 waves
    const int lane = t & 63;
    const int lo4  = lane & 15;
    const int hi2  = lane >> 4;
    const int blk  = blockIdx.x;
    const int qbase = blk * 128;
    const int b    = blk >> 3;
    const int hw0  = (blk & 7) * 128;
    const float* xb = x + (size_t)b * 131072;

    if (t < 8) flagm[t] = 0;
    for (int i = t; i < N_E; i += 512) ee_s[i] = ee[i];

    // ---- phase A: stage x-tile as hi/lo bf16 (swizzled b128 writes) + qq partials
    const int f4 = t & 31;            // queries 4*f4 .. 4*f4+3
    const int cg = t >> 5;            // channel chunk cg: channels cg*8 .. cg*8+7
    float4 xv[8];
    #pragma unroll
    for (int r = 0; r < 8; ++r)
        xv[r] = *reinterpret_cast<const float4*>(xb + (size_t)(cg * 8 + r) * 1024 + hw0 + 4 * f4);
    float qql[4] = {0.f, 0.f, 0.f, 0.f};
    #pragma unroll
    for (int i = 0; i < 4; ++i) {
        const int m = 4 * f4 + i;
        const int sw = (m & 15) ^ (m >> 4);
        short hh[8], ll[8];
        #pragma unroll
        for (int r = 0; r < 8; ++r) {
            const float f = (&xv[r].x)[i];
            qql[i] = fmaf(f, f, qql[i]);
            const unsigned short h = f2bf(f);
            hh[r] = (short)h;
            ll[r] = (short)f2bf(f - bf2f(h));
        }
        const int ch = cg ^ sw;
        *reinterpret_cast<bf16x8*>(&smem[m * 256 + (ch << 3)]) =
            bf16x8{hh[0], hh[1], hh[2], hh[3], hh[4], hh[5], hh[6], hh[7]};
        *reinterpret_cast<bf16x8*>(&smem[m * 256 + 128 + (ch << 3)]) =
            bf16x8{ll[0], ll[1], ll[2], ll[3], ll[4], ll[5], ll[6], ll[7]};
    }
    #pragma unroll
    for (int i = 0; i < 4; ++i) qql[i] += __shfl_xor(qql[i], 32);
    if (lane < 32) {
        #pragma unroll
        for (int i = 0; i < 4; ++i) qqpart[w][4 * lane + i] = qql[i];
    }
    __syncthreads();
    if (t < 128) {
        float s = 0.f;
        #pragma unroll
        for (int ww = 0; ww < 8; ++ww) s += qqpart[ww][t];
        qq[t] = s;
    }
    __syncthreads();

    // ---- A-fragments (qhi, qlo) into registers; wave owns queries mb..mb+15
    const int mb = w * 16;
    const int m_a = mb + lo4;
    const int sw_a = lo4 ^ w;         // SW(m) for m = w*16+lo4
    bf16x8 a_hi[4], a_lo[4];
    #pragma unroll
    for (int ks = 0; ks < 4; ++ks) {
        const int kc = ks * 4 + hi2;
        a_hi[ks] = *reinterpret_cast<const bf16x8*>(&smem[m_a * 256 + ((kc ^ sw_a) << 3)]);
        a_lo[ks] = *reinterpret_cast<const bf16x8*>(&smem[m_a * 256 + 128 + ((kc ^ sw_a) << 3)]);
    }
    float qq_s[4];
    #pragma unroll
    for (int r = 0; r < 4; ++r) qq_s[r] = qq[mb + hi2 * 4 + r];
    __syncthreads();   // all waves done reading x-region; safe to overwrite with B tiles

    // ---- B staging: global_load_lds width16, linear LDS dest, pre-swizzled global src
    auto stage = [&](int jb, int bufsel) {
        #pragma unroll
        for (int j = 0; j < 4; ++j) {
            const int base = w * 256 + j * 64;           // 64-chunk segment, wave-uniform
            const int cidx = base + lane;
            const int seg  = cidx >> 10;                 // 0: ehi, 1: elo
            const int rr   = cidx & 1023;
            const int n    = rr >> 4;
            const int s    = rr & 15;
            const int g    = s ^ (n & 15);
            const unsigned short* src = (seg ? elo : ehi) + (size_t)(jb + n) * CD + g * 8;
            unsigned short* dst = &smem[bufsel * 16384 + base * 8];  // wave-uniform
            __builtin_amdgcn_global_load_lds(
                (const __attribute__((address_space(1))) void*)src,
                (__attribute__((address_space(3))) void*)dst, 16, 0, 0);
        }
    };

    stage(0, 0);
    __syncthreads();   // buf0 ready

    float b1[4], b2[4], sacc[4];
    int   j1[4];
    #pragma unroll
    for (int s = 0; s < 4; ++s) { b1[s] = FLT_MAX; b2[s] = FLT_MAX; sacc[s] = 0.f; j1[s] = 0; }

    #pragma unroll 1
    for (int tile = 0; tile < 16; ++tile) {
        if (tile < 15) stage((tile + 1) * 64, (tile + 1) & 1);   // prefetch next buf

        const unsigned short* bb = &smem[(tile & 1) * 16384];
        const int jb = tile * 64;
        float ee_r[4];
        #pragma unroll
        for (int tn = 0; tn < 4; ++tn) ee_r[tn] = ee_s[jb + tn * 16 + lo4];

        f32x4 acc[4];
        const f32x4 zero = {0.f, 0.f, 0.f, 0.f};
        #pragma unroll
        for (int tn = 0; tn < 4; ++tn) acc[tn] = zero;

        // pass 0: qhi*ehi ; pass 1: qlo*ehi ; pass 2: qhi*elo
        #pragma unroll
        for (int p = 0; p < 3; ++p) {
            const int segoff = (p == 2) ? 8192 : 0;
            #pragma unroll
            for (int ks = 0; ks < 4; ++ks) {
                const int kc = ks * 4 + hi2;
                bf16x8 bfr[4];
                #pragma unroll
                for (int tn = 0; tn < 4; ++tn) {
                    const int n = tn * 16 + lo4;
                    bfr[tn] = *reinterpret_cast<const bf16x8*>(
                        &bb[segoff + n * CD + ((kc ^ (n & 15)) << 3)]);
                }
                #pragma unroll
                for (int tn = 0; tn < 4; ++tn)
                    acc[tn] = __builtin_amdgcn_mfma_f32_16x16x32_bf16(
                        (p == 1) ? a_lo[ks] : a_hi[ks], bfr[tn], acc[tn], 0, 0, 0);
            }
        }

        // ---- fold: d2 ; top-2 ; fixed-frame LSE
        #pragma unroll
        for (int tn = 0; tn < 4; ++tn) {
            const int n = jb + tn * 16 + lo4;
            #pragma unroll
            for (int r = 0; r < 4; ++r) {
                float d2 = fmaf(-2.f, acc[tn][r], qq_s[r] + ee_r[tn]);
                d2 = fmaxf(d2, 0.f);
                b2[r] = fminf(b2[r], fmaxf(b1[r], d2));
                const bool lt = d2 < b1[r];
                j1[r] = lt ? n : j1[r];
                b1[r] = lt ? d2 : b1[r];
                float sd;
                asm("v_sqrt_f32 %0, %1" : "=v"(sd) : "v"(d2));
                sacc[r] += __expf(16.f - sd);
            }
        }

        __syncthreads();   // drains prefetch vmcnt; all waves done reading bb
    }

    // ---- per-wave merge across lo4 (16 lanes share row), flags, loss partial
    unsigned flagbits = 0;
    float lsum = 0.f;
    #pragma unroll
    for (int r = 0; r < 4; ++r) {
        float B1 = b1[r]; int J1 = j1[r]; float B2 = b2[r]; float S = sacc[r];
        #pragma unroll
        for (int d = 1; d <= 8; d <<= 1) {
            const float o1 = __shfl_xor(B1, d);
            const int   oj = __shfl_xor(J1, d);
            const float o2 = __shfl_xor(B2, d);
            const float os = __shfl_xor(S, d);
            const float mx = fmaxf(B1, o1);
            B2 = fminf(fminf(B2, o2), mx);
            const bool take = (o1 < B1) || (o1 == B1 && oj < J1);
            B1 = take ? o1 : B1;
            J1 = take ? oj : J1;
            S += os;
        }
        if (lo4 == 0) {
            const int mloc = hi2 * 4 + r;
            bestjs[mb + mloc] = J1;
            out_idx[qbase + mb + mloc] = (float)J1;
            if (B2 - B1 < DELTA) flagbits |= (1u << mloc);
            lsum += sqrtf(fmaxf(B1, 0.f)) - 16.f + __logf(S);
        }
    }
    if (lo4 == 0) atomicOr(&flagm[w], flagbits);
    lsum += __shfl_down(lsum, 16);
    lsum += __shfl_down(lsum, 32);
    if (lane == 0) partials[blk * 8 + w] = lsum;
    __syncthreads();

    // ---- exact fp32 recheck for near-tie queries (per wave, own rows)
    unsigned fm = flagm[w];
    while (fm) {
        const int mloc = __builtin_ctz(fm);
        fm &= fm - 1;
        const int m = mb + mloc;
        const int hw = hw0 + m;
        qbuf[w][lane]      = xb[(size_t)lane * 1024 + hw];
        qbuf[w][64 + lane] = xb[(size_t)(lane + 64) * 1024 + hw];
        __threadfence_block();
        const float qqm = qq[m];
        float dbest = FLT_MAX; int jbest = 0;
        for (int tt = 0; tt < 16; ++tt) {
            const int j = tt * 64 + lane;
            float dot = 0.f;
            #pragma unroll 8
            for (int c4 = 0; c4 < 32; ++c4) {
                const f32x4 evv = *reinterpret_cast<const f32x4*>(&embed[j * CD + 4 * c4]);
                const f32x4 qv  = *reinterpret_cast<const f32x4*>(&qbuf[w][4 * c4]);
                dot = fmaf(evv[0], qv[0], dot);
                dot = fmaf(evv[1], qv[1], dot);
                dot = fmaf(evv[2], qv[2], dot);
                dot = fmaf(evv[3], qv[3], dot);
            }
            float d2 = fmaf(-2.f, dot, qqm + ee_s[j]);
            d2 = fmaxf(d2, 0.f);
            if (d2 < dbest || (d2 == dbest && j < jbest)) { dbest = d2; jbest = j; }
        }
        #pragma unroll
        for (int d = 1; d <= 32; d <<= 1) {
            const float od = __shfl_xor(dbest, d);
            const int   oj = __shfl_xor(jbest, d);
            if (od < dbest || (od == dbest && oj < jbest)) { dbest = od; jbest = oj; }
        }
        if (lane == 0) {
            bestjs[m] = jbest;
            out_idx[qbase + m] = (float)jbest;
        }
    }
    __syncthreads();

    // ---- gather x_q
    const int jq0 = bestjs[4 * f4 + 0];
    const int jq1 = bestjs[4 * f4 + 1];
    const int jq2 = bestjs[4 * f4 + 2];
    const int jq3 = bestjs[4 * f4 + 3];
    float* ob = out_xq + (size_t)b * 131072 + hw0 + 4 * f4;
    #pragma unroll
    for (int r = 0; r < 8; ++r) {
        const int c = cg * 8 + r;
        float4 v;
        v.x = embed[jq0 * CD + c];
        v.y = embed[jq1 * CD + c];
        v.z = embed[jq2 * CD + c];
        v.w = embed[jq3 * CD + c];
        *reinterpret_cast<float4*>(ob + (size_t)c * 1024) = v;
    }
}

// ---------------- Kernel 3: deterministic loss reduction
__global__ __launch_bounds__(256) void k_loss(const float* __restrict__ partials,
                                              float* __restrict__ out_loss) {
    __shared__ float red[256];
    const int t = threadIdx.x;
    float v = 0.f;
    for (int i = t; i < 4096; i += 256) v += partials[i];
    red[t] = v;
    __syncthreads();
    for (int off = 128; off; off >>= 1) {
        if (t < off) red[t] += red[t + off];
        __syncthreads();
    }
    if (t == 0) out_loss[0] = red[0] * (1.0f / 65536.0f);
}

extern "C" void kernel_launch(void* const* d_in, const int* in_sizes, int n_in,
                              void* d_out, int out_size, void* d_ws, size_t ws_size,
                              hipStream_t stream) {
    const float* x   = (const float*)d_in[0];   // (64,128,32,32)
    const float* emb = (const float*)d_in[1];   // (1024,128)
    const float* pw  = (const float*)d_in[2];   // (128,128)
    const float* pb  = (const float*)d_in[3];   // (128,)

    float* out = (float*)d_out;
    float* out_xq   = out;                 // 8388608 floats
    float* out_loss = out + 8388608;       // 1 float
    float* out_idx  = out + 8388609;       // 65536 floats

    float* embed    = (float*)d_ws;                       // 1024*128 fp32
    float* ee       = embed + N_E * CD;                   // 1024
    float* partials = ee + N_E;                           // 4096
    unsigned short* ehi = (unsigned short*)(partials + 4096);   // 1024*128 bf16
    unsigned short* elo = ehi + N_E * CD;                       // 1024*128 bf16

    k_embed<<<N_E, 128, 0, stream>>>(emb, pw, pb, embed, ee, ehi, elo);
    k_vq<<<512, 512, 0, stream>>>(x, ee, ehi, elo, embed, out_xq, out_idx, partials);
    k_loss<<<1, 256, 0, stream>>>(partials, out_loss);
}